// Round 1
// baseline (91.255 us; speedup 1.0000x reference)
//
#include <hip/hip_runtime.h>
#include <hip/hip_bf16.h>

#define RESV 64
#define DIMV 512
#define HDV 64
#define TWIN 512        // tokens per window (64 y x 8 x)
#define KSTR 68         // K_lds row stride (bf16 elems), padded
#define VSTR 516        // Vt_lds row stride (bf16 elems), padded

typedef __bf16 bf16x8_t __attribute__((ext_vector_type(8)));
typedef float f32x4_t __attribute__((ext_vector_type(4)));

union Frag {
  bf16x8_t v;
  unsigned short u[8];
  unsigned int w[4];
};

__device__ __forceinline__ unsigned short f2bf(float f) {
  unsigned int u = __builtin_bit_cast(unsigned int, f);
  u += 0x7fffu + ((u >> 16) & 1u);
  return (unsigned short)(u >> 16);
}
__device__ __forceinline__ float bf2f(unsigned int h) {
  return __builtin_bit_cast(float, h << 16);
}

__global__ __launch_bounds__(512, 2)
void lepe_attn_kernel(const float* __restrict__ qkv,
                      const float* __restrict__ lw,
                      const float* __restrict__ lb,
                      float* __restrict__ out)
{
  __shared__ unsigned short K_lds[TWIN * KSTR];   // 69632 B
  __shared__ unsigned short Vt_lds[HDV * VSTR];   // 66048 B

  const int head = blockIdx.x & 7;
  const int win  = blockIdx.x >> 3;
  const int bat  = win >> 3;
  const int nw   = win & 7;

  const int tid  = threadIdx.x;
  const int wave = tid >> 6;
  const int lane = tid & 63;
  const int l15  = lane & 15;
  const int g    = lane >> 4;

  const float* qptr = qkv;
  const float* kptr = qkv + 16777216;
  const float* vptr = qkv + 2 * 16777216;

  const int rowbase = bat * 4096;
  // window token t -> global row index: rowbase + (t>>3)*64 + nw*8 + (t&7)

  // ---- stage K ([t][d] row-major) and V^T ([d][t]) into LDS as bf16 ----
  {
    const int tK = wave * 64 + (lane >> 5);
    const int c2 = (lane & 31) * 2;
    #pragma unroll 4
    for (int i = 0; i < 32; ++i) {
      int t = tK + i * 2;
      int grow = rowbase + (t >> 3) * 64 + nw * 8 + (t & 7);
      const float2 f = *(const float2*)(kptr + (size_t)grow * DIMV + head * HDV + c2);
      unsigned int pk = (unsigned int)f2bf(f.x) | ((unsigned int)f2bf(f.y) << 16);
      *(unsigned int*)&K_lds[t * KSTR + c2] = pk;
    }
    #pragma unroll 4
    for (int i = 0; i < 64; ++i) {
      int t = wave * 64 + i;
      int grow = rowbase + (t >> 3) * 64 + nw * 8 + (t & 7);
      float v = vptr[(size_t)grow * DIMV + head * HDV + lane];
      Vt_lds[lane * VSTR + t] = f2bf(v);
    }
  }

  // ---- load Q fragments for this wave's 64 q-rows (B operand of K*Q^T) ----
  const int qbase = wave * 64;
  Frag qf[4][2];
  #pragma unroll
  for (int qi = 0; qi < 4; ++qi) {
    int tok = qbase + qi * 16 + l15;
    int grow = rowbase + (tok >> 3) * 64 + nw * 8 + (tok & 7);
    const float* qp = qptr + (size_t)grow * DIMV + head * HDV;
    #pragma unroll
    for (int kc = 0; kc < 2; ++kc) {
      const float4 f0 = *(const float4*)(qp + kc * 32 + 4 * g);
      const float4 f1 = *(const float4*)(qp + kc * 32 + 4 * g + 16);
      qf[qi][kc].u[0] = f2bf(f0.x); qf[qi][kc].u[1] = f2bf(f0.y);
      qf[qi][kc].u[2] = f2bf(f0.z); qf[qi][kc].u[3] = f2bf(f0.w);
      qf[qi][kc].u[4] = f2bf(f1.x); qf[qi][kc].u[5] = f2bf(f1.y);
      qf[qi][kc].u[6] = f2bf(f1.z); qf[qi][kc].u[7] = f2bf(f1.w);
    }
  }

  __syncthreads();

  const f32x4_t zero4 = {0.f, 0.f, 0.f, 0.f};
  f32x4_t ot[4][4];
  #pragma unroll
  for (int di = 0; di < 4; ++di)
    #pragma unroll
    for (int qi = 0; qi < 4; ++qi)
      ot[di][qi] = zero4;
  float lsum[4] = {0.f, 0.f, 0.f, 0.f};

  // ---- main loop over 8 key tiles of 64 ----
  for (int kt = 0; kt < 8; ++kt) {
    f32x4_t st[4][4];
    #pragma unroll
    for (int ki = 0; ki < 4; ++ki)
      #pragma unroll
      for (int qi = 0; qi < 4; ++qi)
        st[ki][qi] = zero4;

    // S^T = K * Q^T  (M = keys, N = q, K-dim = channels)
    #pragma unroll
    for (int kc = 0; kc < 2; ++kc) {
      Frag kf[4];
      #pragma unroll
      for (int ki = 0; ki < 4; ++ki) {
        const unsigned short* kp = &K_lds[(kt * 64 + ki * 16 + l15) * KSTR + kc * 32 + 4 * g];
        *(uint2*)&kf[ki].w[0] = *(const uint2*)kp;
        *(uint2*)&kf[ki].w[2] = *(const uint2*)(kp + 16);
      }
      #pragma unroll
      for (int ki = 0; ki < 4; ++ki)
        #pragma unroll
        for (int qi = 0; qi < 4; ++qi)
          st[ki][qi] = __builtin_amdgcn_mfma_f32_16x16x32_bf16(
              kf[ki].v, qf[qi][kc].v, st[ki][qi], 0, 0, 0);
    }

    // P^T = exp(scale * S^T); accumulate per-q partial row sums
    #pragma unroll
    for (int ki = 0; ki < 4; ++ki)
      #pragma unroll
      for (int qi = 0; qi < 4; ++qi) {
        f32x4_t s = st[ki][qi];
        #pragma unroll
        for (int r = 0; r < 4; ++r) {
          float p = __expf(s[r] * 0.125f);
          s[r] = p;
          lsum[qi] += p;
        }
        st[ki][qi] = s;
      }

    // O^T += V^T * P^T  (M = d, N = q, K-dim = keys)
    #pragma unroll
    for (int kb = 0; kb < 2; ++kb) {
      Frag vf[4];
      #pragma unroll
      for (int di = 0; di < 4; ++di) {
        const unsigned short* vp = &Vt_lds[(di * 16 + l15) * VSTR + kt * 64 + kb * 32 + 4 * g];
        *(uint2*)&vf[di].w[0] = *(const uint2*)vp;
        *(uint2*)&vf[di].w[2] = *(const uint2*)(vp + 16);
      }
      #pragma unroll
      for (int qi = 0; qi < 4; ++qi) {
        Frag pb;
        #pragma unroll
        for (int r = 0; r < 4; ++r) {
          pb.u[r]     = f2bf(st[2 * kb][qi][r]);
          pb.u[4 + r] = f2bf(st[2 * kb + 1][qi][r]);
        }
        #pragma unroll
        for (int di = 0; di < 4; ++di)
          ot[di][qi] = __builtin_amdgcn_mfma_f32_16x16x32_bf16(
              vf[di].v, pb.v, ot[di][qi], 0, 0, 0);
      }
    }
  }

  // ---- finish softmax denominators (reduce across lane>>4 groups) ----
  float rl[4];
  #pragma unroll
  for (int qi = 0; qi < 4; ++qi) {
    float s = lsum[qi];
    s += __shfl_xor(s, 16, 64);
    s += __shfl_xor(s, 32, 64);
    rl[qi] = 1.0f / s;
  }

  __syncthreads();   // all waves done reading K_lds; reuse it for LePE

  // ---- LePE: depthwise 3x3 conv, lane = channel, 8x8 patch per wave ----
  unsigned short* lepe = &K_lds[wave * 64 * KSTR];
  {
    float wgt[9];
    const float* wp = lw + (size_t)(head * HDV + lane) * 9;
    #pragma unroll
    for (int tp = 0; tp < 9; ++tp) wgt[tp] = wp[tp];
    const float bias = lb[head * HDV + lane];
    const int y0 = wave * 8;

    float rm[8], rc[8], rp[8];
    auto loadrow = [&](int y, float* dst) {
      if (y < 0 || y > 63) {
        #pragma unroll
        for (int x = 0; x < 8; ++x) dst[x] = 0.f;
        return;
      }
      const unsigned short* p = &Vt_lds[lane * VSTR + y * 8];
      uint2 a = *(const uint2*)p;
      uint2 c = *(const uint2*)(p + 4);
      dst[0] = bf2f(a.x & 0xffffu); dst[1] = bf2f(a.x >> 16);
      dst[2] = bf2f(a.y & 0xffffu); dst[3] = bf2f(a.y >> 16);
      dst[4] = bf2f(c.x & 0xffffu); dst[5] = bf2f(c.x >> 16);
      dst[6] = bf2f(c.y & 0xffffu); dst[7] = bf2f(c.y >> 16);
    };
    loadrow(y0 - 1, rm);
    loadrow(y0, rc);
    for (int yy = 0; yy < 8; ++yy) {
      loadrow(y0 + yy + 1, rp);
      #pragma unroll
      for (int x = 0; x < 8; ++x) {
        float acc = bias;
        if (x > 0) acc += rm[x - 1] * wgt[0] + rc[x - 1] * wgt[3] + rp[x - 1] * wgt[6];
        acc += rm[x] * wgt[1] + rc[x] * wgt[4] + rp[x] * wgt[7];
        if (x < 7) acc += rm[x + 1] * wgt[2] + rc[x + 1] * wgt[5] + rp[x + 1] * wgt[8];
        lepe[(yy * 8 + x) * KSTR + lane] = f2bf(acc);
      }
      #pragma unroll
      for (int x = 0; x < 8; ++x) { rm[x] = rc[x]; rc[x] = rp[x]; }
    }
  }

  __syncthreads();

  // ---- normalize, add LePE, store ----
  #pragma unroll
  for (int qi = 0; qi < 4; ++qi) {
    int tloc = qi * 16 + l15;
    int tok = qbase + tloc;
    int grow = rowbase + (tok >> 3) * 64 + nw * 8 + (tok & 7);
    float* op = out + (size_t)grow * DIMV + head * HDV;
    #pragma unroll
    for (int di = 0; di < 4; ++di) {
      const unsigned short* lp = &lepe[tloc * KSTR + di * 16 + 4 * g];
      uint2 lv = *(const uint2*)lp;
      float4 o;
      o.x = ot[di][qi][0] * rl[qi] + bf2f(lv.x & 0xffffu);
      o.y = ot[di][qi][1] * rl[qi] + bf2f(lv.x >> 16);
      o.z = ot[di][qi][2] * rl[qi] + bf2f(lv.y & 0xffffu);
      o.w = ot[di][qi][3] * rl[qi] + bf2f(lv.y >> 16);
      *(float4*)(op + di * 16 + 4 * g) = o;
    }
  }
}

extern "C" void kernel_launch(void* const* d_in, const int* in_sizes, int n_in,
                              void* d_out, int out_size, void* d_ws, size_t ws_size,
                              hipStream_t stream) {
  const float* qkv = (const float*)d_in[0];
  const float* lw  = (const float*)d_in[1];
  const float* lb  = (const float*)d_in[2];
  float* out = (float*)d_out;
  (void)in_sizes; (void)n_in; (void)out_size; (void)d_ws; (void)ws_size;

  dim3 grid(512);   // 64 windows x 8 heads
  dim3 block(512);  // 8 waves
  hipLaunchKernelGGL(lepe_attn_kernel, grid, block, 0, stream, qkv, lw, lb, out);
}